// Round 3
// baseline (92.966 us; speedup 1.0000x reference)
//
#include <hip/hip_runtime.h>
#include <hip/hip_bf16.h>
#include <math.h>

// Problem constants
#define BATCH   4096
#define DIM     512
#define DIMB    256                         // bytes per fp4 row
#define TWO_B   8192
#define INV_T   10.0f                       // 1/TEMP
#define LSE_SCALE 14.426950408889634f       // log2(e)/TEMP
#define NTRI    2080                        // 64*65/2 upper-triangle tiles

typedef __attribute__((ext_vector_type(8)))  int   intx8;
typedef __attribute__((ext_vector_type(4)))  int   intx4;
typedef __attribute__((ext_vector_type(16))) float floatx16; // 32x32 MFMA acc

// E8M0 scale byte: 2^(x-127). 122 -> 2^-5 per operand (z stored x32; 2^-10
// total undoes 32*32).
#define SCALE_E8M0 122
#define FMT_FP4 4                           // cbsz/blgp encoding for fp4 e2m1

// async global->LDS, 16B/lane, linear LDS dest (wave-uniform base + lane*16)
#define LOAD_LDS_16(gaddr, laddr)                                             \
    __builtin_amdgcn_global_load_lds(                                         \
        (const __attribute__((address_space(1))) unsigned int*)(gaddr),       \
        (__attribute__((address_space(3))) unsigned int*)(laddr), 16, 0, 0)

// SESSION LESSONS (measured):
//  - __threadfence() per block on gfx950 => per-XCD L2 writeback: ~+97 us.
//  - 266k device-scope atomics + completion counter: +14 us vs 3-kernel split.
//  - PER-SLAB LDS staging with in-loop barriers lost to direct L2 gathers.
//    (Whole-panel staging + barrier-free ds_read K-loop is a different
//    structure - this round's change.)
//  - R0->R2: register double-buffer prefetch of global loads = -3.4 us only
//    (compiler already schedules; m131-m140 lesson reproduced).
//  - ACCOUNTING (R2): dur_us = one 256MiB harness poison fill (~42 us,
//    stream-serialized, un-removable) + our kernels (~43 us). Each of our
//    kernels < 43 us (below top-5 fill cutoff); sim ~ 35 us inferred ->
//    latency-bound barrier-free K-loop on ~250 cy L2 hits at 3 waves/SIMD.

// e2m1 encode of |v|<=~6 with round-to-nearest. Values: 0,.5,1,1.5,2,3,4,6.
static __device__ inline unsigned fp4_enc(float v) {
    const unsigned s = (__float_as_uint(v) >> 28) & 8u;   // sign -> bit3
    const float a = fabsf(v);
    unsigned c;
    if      (a < 0.25f) c = 0;
    else if (a < 0.75f) c = 1;
    else if (a < 1.25f) c = 2;
    else if (a < 1.75f) c = 3;
    else if (a < 2.5f)  c = 4;
    else if (a < 3.5f)  c = 5;
    else if (a < 5.0f)  c = 6;
    else                c = 7;
    return s | c;
}

// Fragment-order z4 layout: for global row R and row-byte t (elements
// 2t,2t+1) the byte lives at
//   (R>>5)*8192 + (t>>5)*1024 + ((t>>4)&1)*512 + (R&31)*16 + (t&15)
// so an MFMA A/B fragment load (row-block rb, slab s, lane = r + 32*c) is
// ONE contiguous 1 KB segment: rb*8192 + s*1024 + c*512 + r*16.
static __device__ inline size_t z4t_addr(int R, int t) {
    return (size_t)(R >> 5) * 8192 + (size_t)(t >> 5) * 1024 +
           (size_t)((t >> 4) & 1) * 512 + (size_t)(R & 31) * 16 + (t & 15);
}

// ---------------------------------------------------------------------------
// Kernel 1: L2-normalize pairs. ONE WAVE PER ROW-PAIR (barrier-free):
// lane owns elements 8l..8l+7 (= row-bytes 4l..4l+3, one aligned u32 in
// fragment order). shfl_xor butterfly gives every lane the norms; no LDS,
// no __syncthreads. Also zeroes out[0] (stream-ordered before lse).
// ---------------------------------------------------------------------------
__global__ __launch_bounds__(256) void norm_kernel(
    const float* __restrict__ p1, const float* __restrict__ p2,
    unsigned char* __restrict__ z4, float* __restrict__ pos,
    float* __restrict__ out)
{
    const int wave = threadIdx.x >> 6, lane = threadIdx.x & 63;
    const int i = blockIdx.x * 4 + wave;          // 0..4095

    if (blockIdx.x == 0 && threadIdx.x == 0) out[0] = 0.0f;

    const float4* px = (const float4*)(p1 + (size_t)i * DIM);
    const float4* py = (const float4*)(p2 + (size_t)i * DIM);
    const float4 x0 = px[lane * 2], x1 = px[lane * 2 + 1];
    const float4 y0 = py[lane * 2], y1 = py[lane * 2 + 1];

    float sx = x0.x * x0.x, sy = y0.x * y0.x, sd = x0.x * y0.x;
    sx = fmaf(x0.y, x0.y, sx); sy = fmaf(y0.y, y0.y, sy); sd = fmaf(x0.y, y0.y, sd);
    sx = fmaf(x0.z, x0.z, sx); sy = fmaf(y0.z, y0.z, sy); sd = fmaf(x0.z, y0.z, sd);
    sx = fmaf(x0.w, x0.w, sx); sy = fmaf(y0.w, y0.w, sy); sd = fmaf(x0.w, y0.w, sd);
    sx = fmaf(x1.x, x1.x, sx); sy = fmaf(y1.x, y1.x, sy); sd = fmaf(x1.x, y1.x, sd);
    sx = fmaf(x1.y, x1.y, sx); sy = fmaf(y1.y, y1.y, sy); sd = fmaf(x1.y, y1.y, sd);
    sx = fmaf(x1.z, x1.z, sx); sy = fmaf(y1.z, y1.z, sy); sd = fmaf(x1.z, y1.z, sd);
    sx = fmaf(x1.w, x1.w, sx); sy = fmaf(y1.w, y1.w, sy); sd = fmaf(x1.w, y1.w, sd);

    #pragma unroll
    for (int off = 1; off < 64; off <<= 1) {      // butterfly: all lanes get sums
        sx += __shfl_xor(sx, off);
        sy += __shfl_xor(sy, off);
        sd += __shfl_xor(sd, off);
    }

    const float rx = 1.0f / fmaxf(sqrtf(sx), 1e-12f);
    const float ry = 1.0f / fmaxf(sqrtf(sy), 1e-12f);
    const float gx = 32.0f * rx, gy = 32.0f * ry; // x32 -> sigma ~1.4 in fp4

    const float xs[8] = {x0.x, x0.y, x0.z, x0.w, x1.x, x1.y, x1.z, x1.w};
    const float ys[8] = {y0.x, y0.y, y0.z, y0.w, y1.x, y1.y, y1.z, y1.w};
    unsigned zx = 0, zy = 0;
    #pragma unroll
    for (int j = 0; j < 8; ++j) {
        zx |= fp4_enc(xs[j] * gx) << (4 * j);
        zy |= fp4_enc(ys[j] * gy) << (4 * j);
    }
    // bytes 4l..4l+3 are contiguous & 4-aligned in fragment order
    *(unsigned*)(z4 + z4t_addr(i, lane * 4)) = zx;
    *(unsigned*)(z4 + z4t_addr(i + BATCH, lane * 4)) = zy;

    if (lane == 0) pos[i] = sd * rx * ry * INV_T;
}

// ---------------------------------------------------------------------------
// Kernel 2: UPPER-TRIANGLE fused z@z^T tiles in MX-FP4.
// NEW STRUCTURE (this round): whole-panel LDS staging. Each block stages its
// 32 KB A-panel + 32 KB B-panel ONCE via global_load_lds width-16 (panel is
// contiguous in fragment-ordered z4t; linear LDS dest = legal gload_lds
// pattern), ONE barrier, then the K-loop is pure ds_read_b128 (+MFMA):
// ~120 cy LDS latency instead of ~250 cy L2 latency per slab, zero global
// loads and zero barriers in the loop. L2 traffic halves (panel loaded once
// per block, not once per wave). LDS = exactly 64 KB -> 2 blocks/CU;
// epilogue rowbuf/colred alias the dead panel space after a barrier.
// s_setprio(1) around the MFMA quad (waves phase-staggered, attn-like).
// Epilogue: exp2 + diag mask; colsum in-lane; rowsum via 2-phase LDS
// transpose; plain stores (every slot written exactly once, no atomics).
// ---------------------------------------------------------------------------
__global__ __launch_bounds__(256, 2) void sim_kernel(
    const unsigned char* __restrict__ z4, float* __restrict__ partial)
{
    __shared__ __align__(16) unsigned char smem[65536];
    unsigned char* ldsA = smem;                 // [4][8][1024] fragment order
    unsigned char* ldsB = smem + 32768;
    float* rowbuf = (float*)smem;               // [64][68] f32 (aliases panels)
    float* colred = (float*)(smem + 17408);     // [128*5] f32  (aliases panels)

    // --- triangular decode: blockIdx.x -> (rt, ct), rt <= ct --------------
    const int idx = blockIdx.x;
    int rt = (int)((129.0 - sqrt(16641.0 - 8.0 * (double)idx)) * 0.5);
    while (64 * (rt + 1) - ((rt + 1) * rt) / 2 <= idx) ++rt;
    while (64 * rt - (rt * (rt - 1)) / 2 > idx) --rt;
    const int ct = rt + (idx - (64 * rt - (rt * (rt - 1)) / 2));
    const bool diag = (rt == ct);

    const int t = threadIdx.x;
    const int wave = t >> 6, lane = t & 63;
    const int wr = wave >> 1, wc = wave & 1;   // 2x2 wave grid, 64x64 each
    const int lrow  = lane & 31;               // m/n within a 32-tile
    const int lhalf = lane >> 5;               // k-half (chunk) selector

    // --- stage panels: wave w copies its 8 KB quarter of A and of B -------
    const unsigned char* gA = z4 + (size_t)rt * 32768;
    const unsigned char* gB = z4 + (size_t)ct * 32768;
    const int wq = wave * 8192;
    #pragma unroll
    for (int k = 0; k < 8; ++k) {
        LOAD_LDS_16(gA + wq + k * 1024 + lane * 16, ldsA + wq + k * 1024);
        LOAD_LDS_16(gB + wq + k * 1024 + lane * 16, ldsB + wq + k * 1024);
    }

    floatx16 acc[2][2];
    #pragma unroll
    for (int mi = 0; mi < 2; ++mi)
        #pragma unroll
        for (int ni = 0; ni < 2; ++ni)
            acc[mi][ni] = (floatx16)0.0f;

    __syncthreads();   // drains vmcnt(0): panels resident

    // --- K-loop: 8 slabs x {4 ds_read_b128 -> 4 MFMA}, no barriers --------
    const int loff = lhalf * 512 + lrow * 16;  // contiguous 1 KB per wave: no
    const unsigned char* Ab = ldsA + (size_t)(wr * 2) * 8192 + loff;   // bank
    const unsigned char* Bb = ldsB + (size_t)(wc * 2) * 8192 + loff;   // conflicts

    #pragma unroll
    for (int s = 0; s < 8; ++s) {
        intx8 af[2], bf[2];
        #pragma unroll
        for (int mi = 0; mi < 2; ++mi) {
            const intx4 a0 = *(const intx4*)(Ab + mi * 8192 + s * 1024);
            const intx4 b0 = *(const intx4*)(Bb + mi * 8192 + s * 1024);
            #pragma unroll
            for (int j = 0; j < 4; ++j) {
                af[mi][j] = a0[j]; af[mi][j + 4] = 0;
                bf[mi][j] = b0[j]; bf[mi][j + 4] = 0;
            }
        }
        __builtin_amdgcn_s_setprio(1);
        #pragma unroll
        for (int mi = 0; mi < 2; ++mi)
            #pragma unroll
            for (int ni = 0; ni < 2; ++ni)
                acc[mi][ni] = __builtin_amdgcn_mfma_scale_f32_32x32x64_f8f6f4(
                    af[mi], bf[ni], acc[mi][ni],
                    FMT_FP4, FMT_FP4,           // cbsz, blgp = fp4 e2m1
                    0, SCALE_E8M0,              // opsel_a, scale_a (2^-5)
                    0, SCALE_E8M0);             // opsel_b, scale_b (2^-5)
        __builtin_amdgcn_s_setprio(0);
    }

    __syncthreads();   // panels dead; epilogue may reuse the LDS

    // --- epilogue ----------------------------------------------------------
    // C/D layout (shape-determined): col = lane&31,
    // row = (reg&3) + 8*(reg>>2) + 4*(lane>>5), within each 32x32 tile.
    // Self-mask only possible when wr==wc && mi==ni && rsub==lrow.
    const bool dwave = diag && (wr == wc);

    float cs[2] = {0.0f, 0.0f};     // per-column sums (2 cols this lane owns)
    float rw[2][16];                // per-row partials (summed over ni in-lane)
    #pragma unroll
    for (int mi = 0; mi < 2; ++mi)
        #pragma unroll
        for (int r = 0; r < 16; ++r)
            rw[mi][r] = 0.0f;

    #pragma unroll
    for (int mi = 0; mi < 2; ++mi) {
        #pragma unroll
        for (int ni = 0; ni < 2; ++ni) {
            #pragma unroll
            for (int r = 0; r < 16; ++r) {
                const int rsub = lhalf * 4 + (r & 3) + 8 * (r >> 2);
                float ee = __builtin_amdgcn_exp2f(acc[mi][ni][r] * LSE_SCALE);
                if (mi == ni && dwave && rsub == lrow) ee = 0.0f; // -inf self
                cs[ni] += ee;
                rw[mi][r] += ee;
            }
        }
    }

    // col sums -> colred (4 partials/column, stride-5); rowbuf phase-0 now.
    const int slot = wr * 2 + lhalf;
    #pragma unroll
    for (int ni = 0; ni < 2; ++ni)
        colred[(wc * 64 + ni * 32 + lrow) * 5 + slot] = cs[ni];
    if (!diag && wr == 0) {
        #pragma unroll
        for (int mi = 0; mi < 2; ++mi)
            #pragma unroll
            for (int r = 0; r < 16; ++r) {
                const int lr = mi * 32 + lhalf * 4 + (r & 3) + 8 * (r >> 2);
                rowbuf[lr * 68 + wc * 32 + lrow] = rw[mi][r];
            }
    }
    __syncthreads();

    if (t < 128) {
        const float s = colred[t * 5 + 0] + colred[t * 5 + 1] +
                        colred[t * 5 + 2] + colred[t * 5 + 3];
        partial[(size_t)rt * TWO_B + (size_t)ct * 128 + t] = s;
    }

    if (!diag) {
        // phase-0 read (tile rows 0..63)
        if (t < 128) {
            const int r = t >> 1, h = t & 1;
            const float4* rb = (const float4*)(rowbuf + r * 68 + h * 32);
            float s = 0.0f;
            #pragma unroll
            for (int j = 0; j < 8; ++j) {
                const float4 v = rb[j];
                s += (v.x + v.y) + (v.z + v.w);
            }
            s += __shfl_xor(s, 1, 64);
            if (h == 0)
                partial[(size_t)ct * TWO_B + (size_t)rt * 128 + r] = s;
        }
        __syncthreads();
        if (wr == 1) {                 // phase-1 write (tile rows 64..127)
            #pragma unroll
            for (int mi = 0; mi < 2; ++mi)
                #pragma unroll
                for (int r = 0; r < 16; ++r) {
                    const int lr = mi * 32 + lhalf * 4 + (r & 3) + 8 * (r >> 2);
                    rowbuf[lr * 68 + wc * 32 + lrow] = rw[mi][r];
                }
        }
        __syncthreads();
        if (t < 128) {
            const int r = t >> 1, h = t & 1;
            const float4* rb = (const float4*)(rowbuf + r * 68 + h * 32);
            float s = 0.0f;
            #pragma unroll
            for (int j = 0; j < 8; ++j) {
                const float4 v = rb[j];
                s += (v.x + v.y) + (v.z + v.w);
            }
            s += __shfl_xor(s, 1, 64);
            if (h == 0)
                partial[(size_t)ct * TWO_B + (size_t)rt * 128 + 64 + r] = s;
        }
    }
}

// ---------------------------------------------------------------------------
// Kernel 3: per-row sumexp over 64 tile contributions -> lse - pos term.
// 128 blocks: block handles 64 rows; wave w sums 16 tiles for all 64 rows
// (coalesced 256 B loads, 16 independent in flight), one LDS combine, one
// atomic per block.
// ---------------------------------------------------------------------------
__global__ __launch_bounds__(256) void lse_kernel(
    const float* __restrict__ partial, const float* __restrict__ pos,
    float* __restrict__ out)
{
    const int t = threadIdx.x;
    const int wave = t >> 6, lane = t & 63;
    const int row0 = blockIdx.x * 64;

    float s = 0.0f;
    #pragma unroll
    for (int j = 0; j < 16; ++j)
        s += partial[(size_t)(wave * 16 + j) * TWO_B + row0 + lane];

    __shared__ float red[4][64];
    red[wave][lane] = s;
    __syncthreads();

    if (wave == 0) {
        const int row = row0 + lane;
        const float tot = red[0][lane] + red[1][lane] +
                          red[2][lane] + red[3][lane];
        float term = logf(tot) - pos[row & (BATCH - 1)];  // sim_ij == sim_ji
        #pragma unroll
        for (int off = 32; off > 0; off >>= 1)
            term += __shfl_down(term, off);
        if (lane == 0)
            atomicAdd(out, term * (1.0f / (float)TWO_B));
    }
}

// ---------------------------------------------------------------------------
extern "C" void kernel_launch(void* const* d_in, const int* in_sizes, int n_in,
                              void* d_out, int out_size, void* d_ws, size_t ws_size,
                              hipStream_t stream)
{
    const float* p1 = (const float*)d_in[0];
    const float* p2 = (const float*)d_in[1];
    float* out = (float*)d_out;

    // Workspace layout (all fully rewritten every call; poison-safe):
    //   z4t      : 8192*256 fp4 (fragment-ordered) = 2,097,152 B
    //   pos      : 4096 f32                        =    16,384 B
    //   partial  : 64*8192 f32                     = 2,097,152 B
    char* ws = (char*)d_ws;
    unsigned char* z4  = (unsigned char*)ws;
    float* pos         = (float*)(ws + 2097152);
    float* partial     = (float*)(ws + 2097152 + 16384);

    norm_kernel<<<1024, 256, 0, stream>>>(p1, p2, z4, pos, out);
    sim_kernel<<<NTRI, 256, 0, stream>>>(z4, partial);
    lse_kernel<<<128, 256, 0, stream>>>(partial, pos, out);
}

// Round 4
// 89.307 us; speedup vs baseline: 1.0410x; 1.0410x over previous
//
#include <hip/hip_runtime.h>
#include <hip/hip_bf16.h>
#include <math.h>

// Problem constants
#define BATCH   4096
#define DIM     512
#define DIMB    256                         // bytes per fp4 row
#define TWO_B   8192
#define INV_T   10.0f                       // 1/TEMP
#define LSE_SCALE 14.426950408889634f       // log2(e)/TEMP
#define NTRI    2080                        // 64*65/2 upper-triangle tiles

typedef __attribute__((ext_vector_type(8)))  int   intx8;
typedef __attribute__((ext_vector_type(4)))  int   intx4;
typedef __attribute__((ext_vector_type(16))) float floatx16; // 32x32 MFMA acc

// E8M0 scale byte: 2^(x-127). 122 -> 2^-5 per operand (z stored x32; 2^-10
// total undoes 32*32).
#define SCALE_E8M0 122
#define FMT_FP4 4                           // cbsz/blgp encoding for fp4 e2m1

// SESSION LESSONS (measured):
//  - __threadfence() per block on gfx950 => per-XCD L2 writeback: ~+97 us.
//  - 266k device-scope atomics + completion counter: +14 us vs 3-kernel split.
//  - LDS staging in sim's K-loop loses to direct L2 gathers IN BOTH FORMS:
//    per-slab w/ barriers (prior session) AND whole-panel gload_lds +
//    barrier-free ds_read loop (R3: +6.6 us; staging has no compute cover,
//    and 64KB LDS costs a block of occupancy). Direct-L2 is right for this
//    2 MB L2/L3-resident operand.
//  - R0->R2: 2-deep register prefetch = -3.4 us only (covers 142 cy of the
//    ~300-600 cy L2/L3 latency; insufficient).
//  - ACCOUNTING (R2/R3): dur_us = one 256 MiB harness poison fill (~43 us,
//    stream-serialized, un-removable) + our kernels (~43 us R2). MFMA floor
//    for sim is 3.9 us (35 cy/MFMA per SIMD); ~25 us unexplained -> this
//    round: one latency exposure per wave (all 32 K-loop loads in flight).

// e2m1 encode of |v|<=~6 with round-to-nearest. Values: 0,.5,1,1.5,2,3,4,6.
static __device__ inline unsigned fp4_enc(float v) {
    const unsigned s = (__float_as_uint(v) >> 28) & 8u;   // sign -> bit3
    const float a = fabsf(v);
    unsigned c;
    if      (a < 0.25f) c = 0;
    else if (a < 0.75f) c = 1;
    else if (a < 1.25f) c = 2;
    else if (a < 1.75f) c = 3;
    else if (a < 2.5f)  c = 4;
    else if (a < 3.5f)  c = 5;
    else if (a < 5.0f)  c = 6;
    else                c = 7;
    return s | c;
}

// Fragment-order z4 layout: for global row R and row-byte t (elements
// 2t,2t+1) the byte lives at
//   (R>>5)*8192 + (t>>5)*1024 + ((t>>4)&1)*512 + (R&31)*16 + (t&15)
// so an MFMA A/B fragment load (row-block rb, slab s, lane = r + 32*c) is
// ONE contiguous 1 KB segment: rb*8192 + s*1024 + c*512 + r*16.
static __device__ inline size_t z4t_addr(int R, int t) {
    return (size_t)(R >> 5) * 8192 + (size_t)(t >> 5) * 1024 +
           (size_t)((t >> 4) & 1) * 512 + (size_t)(R & 31) * 16 + (t & 15);
}

// ---------------------------------------------------------------------------
// Kernel 1: L2-normalize pairs. ONE WAVE PER ROW-PAIR (barrier-free):
// lane owns elements 8l..8l+7 (= row-bytes 4l..4l+3, one aligned u32 in
// fragment order). shfl_xor butterfly gives every lane the norms; no LDS,
// no __syncthreads. Also zeroes out[0] (stream-ordered before lse).
// ---------------------------------------------------------------------------
__global__ __launch_bounds__(256) void norm_kernel(
    const float* __restrict__ p1, const float* __restrict__ p2,
    unsigned char* __restrict__ z4, float* __restrict__ pos,
    float* __restrict__ out)
{
    const int wave = threadIdx.x >> 6, lane = threadIdx.x & 63;
    const int i = blockIdx.x * 4 + wave;          // 0..4095

    if (blockIdx.x == 0 && threadIdx.x == 0) out[0] = 0.0f;

    const float4* px = (const float4*)(p1 + (size_t)i * DIM);
    const float4* py = (const float4*)(p2 + (size_t)i * DIM);
    const float4 x0 = px[lane * 2], x1 = px[lane * 2 + 1];
    const float4 y0 = py[lane * 2], y1 = py[lane * 2 + 1];

    float sx = x0.x * x0.x, sy = y0.x * y0.x, sd = x0.x * y0.x;
    sx = fmaf(x0.y, x0.y, sx); sy = fmaf(y0.y, y0.y, sy); sd = fmaf(x0.y, y0.y, sd);
    sx = fmaf(x0.z, x0.z, sx); sy = fmaf(y0.z, y0.z, sy); sd = fmaf(x0.z, y0.z, sd);
    sx = fmaf(x0.w, x0.w, sx); sy = fmaf(y0.w, y0.w, sy); sd = fmaf(x0.w, y0.w, sd);
    sx = fmaf(x1.x, x1.x, sx); sy = fmaf(y1.x, y1.x, sy); sd = fmaf(x1.x, y1.x, sd);
    sx = fmaf(x1.y, x1.y, sx); sy = fmaf(y1.y, y1.y, sy); sd = fmaf(x1.y, y1.y, sd);
    sx = fmaf(x1.z, x1.z, sx); sy = fmaf(y1.z, y1.z, sy); sd = fmaf(x1.z, y1.z, sd);
    sx = fmaf(x1.w, x1.w, sx); sy = fmaf(y1.w, y1.w, sy); sd = fmaf(x1.w, y1.w, sd);

    #pragma unroll
    for (int off = 1; off < 64; off <<= 1) {      // butterfly: all lanes get sums
        sx += __shfl_xor(sx, off);
        sy += __shfl_xor(sy, off);
        sd += __shfl_xor(sd, off);
    }

    const float rx = 1.0f / fmaxf(sqrtf(sx), 1e-12f);
    const float ry = 1.0f / fmaxf(sqrtf(sy), 1e-12f);
    const float gx = 32.0f * rx, gy = 32.0f * ry; // x32 -> sigma ~1.4 in fp4

    const float xs[8] = {x0.x, x0.y, x0.z, x0.w, x1.x, x1.y, x1.z, x1.w};
    const float ys[8] = {y0.x, y0.y, y0.z, y0.w, y1.x, y1.y, y1.z, y1.w};
    unsigned zx = 0, zy = 0;
    #pragma unroll
    for (int j = 0; j < 8; ++j) {
        zx |= fp4_enc(xs[j] * gx) << (4 * j);
        zy |= fp4_enc(ys[j] * gy) << (4 * j);
    }
    // bytes 4l..4l+3 are contiguous & 4-aligned in fragment order
    *(unsigned*)(z4 + z4t_addr(i, lane * 4)) = zx;
    *(unsigned*)(z4 + z4t_addr(i + BATCH, lane * 4)) = zy;

    if (lane == 0) pos[i] = sd * rx * ry * INV_T;
}

// ---------------------------------------------------------------------------
// Kernel 2: UPPER-TRIANGLE fused z@z^T tiles in MX-FP4, direct-L2 K-loop
// (LDS staging reverted — R3 lesson). NEW: FLAT-UNROLLED K — all 32 fragment
// loads (8 slabs x 2 frags x {A,B}, one coalesced 1 KB dwordx4 per wave per
// fragment) issued up front into registers (~128 VGPR in flight), then the
// 32 MFMAs run back-to-back. One L2-latency exposure per wave instead of 8.
// __launch_bounds__(256,2): 256-reg budget, no spill (all indices static).
// Epilogue: exp2 + diag mask; colsum in-lane; rowsum via SINGLE-PHASE LDS
// transpose (rowbuf now holds all 128 rows; ONE __syncthreads, was 3);
// plain stores (every slot written exactly once -> no atomics).
// ---------------------------------------------------------------------------
__global__ __launch_bounds__(256, 2) void sim_kernel(
    const unsigned char* __restrict__ z4, float* __restrict__ partial)
{
    __shared__ __align__(16) unsigned char smem[37376];
    float* rowbuf = (float*)smem;               // [128][68] f32 = 34816 B
    float* colred = (float*)(smem + 34816);     // [128*5]  f32 =  2560 B

    // --- triangular decode: blockIdx.x -> (rt, ct), rt <= ct --------------
    const int idx = blockIdx.x;
    int rt = (int)((129.0 - sqrt(16641.0 - 8.0 * (double)idx)) * 0.5);
    while (64 * (rt + 1) - ((rt + 1) * rt) / 2 <= idx) ++rt;
    while (64 * rt - (rt * (rt - 1)) / 2 > idx) --rt;
    const int ct = rt + (idx - (64 * rt - (rt * (rt - 1)) / 2));
    const bool diag = (rt == ct);

    const int t = threadIdx.x;
    const int wave = t >> 6, lane = t & 63;
    const int wr = wave >> 1, wc = wave & 1;   // 2x2 wave grid, 64x64 each
    const int lrow  = lane & 31;               // m/n within a 32-tile
    const int lhalf = lane >> 5;               // k-half (chunk) selector

    // Per-lane byte offset within a (row-block, slab) 1 KB segment.
    const int loff = lhalf * 512 + lrow * 16;
    const unsigned char* Abase = z4 + (size_t)(rt * 4 + wr * 2) * 8192 + loff;
    const unsigned char* Bbase = z4 + (size_t)(ct * 4 + wc * 2) * 8192 + loff;

    // --- flat-unrolled K: issue ALL 32 loads, then 32 MFMAs ---------------
    intx4 pa[8][2], pb[8][2];                   // 128 VGPRs in flight
    #pragma unroll
    for (int s = 0; s < 8; ++s)
        #pragma unroll
        for (int mi = 0; mi < 2; ++mi) {
            pa[s][mi] = *(const intx4*)(Abase + mi * 8192 + s * 1024);
            pb[s][mi] = *(const intx4*)(Bbase + mi * 8192 + s * 1024);
        }

    floatx16 acc[2][2];
    #pragma unroll
    for (int mi = 0; mi < 2; ++mi)
        #pragma unroll
        for (int ni = 0; ni < 2; ++ni)
            acc[mi][ni] = (floatx16)0.0f;

    #pragma unroll
    for (int s = 0; s < 8; ++s) {
        intx8 af[2], bf[2];
        #pragma unroll
        for (int mi = 0; mi < 2; ++mi)
            #pragma unroll
            for (int j = 0; j < 4; ++j) {       // upper 4 ints stay zero
                af[mi][j] = pa[s][mi][j]; af[mi][j + 4] = 0;
                bf[mi][j] = pb[s][mi][j]; bf[mi][j + 4] = 0;
            }
        __builtin_amdgcn_s_setprio(1);
        #pragma unroll
        for (int mi = 0; mi < 2; ++mi)
            #pragma unroll
            for (int ni = 0; ni < 2; ++ni)
                acc[mi][ni] = __builtin_amdgcn_mfma_scale_f32_32x32x64_f8f6f4(
                    af[mi], bf[ni], acc[mi][ni],
                    FMT_FP4, FMT_FP4,           // cbsz, blgp = fp4 e2m1
                    0, SCALE_E8M0,              // opsel_a, scale_a (2^-5)
                    0, SCALE_E8M0);             // opsel_b, scale_b (2^-5)
        __builtin_amdgcn_s_setprio(0);
    }

    // --- epilogue ----------------------------------------------------------
    // C/D layout (shape-determined): col = lane&31,
    // row = (reg&3) + 8*(reg>>2) + 4*(lane>>5), within each 32x32 tile.
    // Self-mask only possible when wr==wc && mi==ni && rsub==lrow.
    const bool dwave = diag && (wr == wc);

    float cs[2] = {0.0f, 0.0f};     // per-column sums (2 cols this lane owns)
    float rw[2][16];                // per-row partials (summed over ni in-lane)
    #pragma unroll
    for (int mi = 0; mi < 2; ++mi)
        #pragma unroll
        for (int r = 0; r < 16; ++r)
            rw[mi][r] = 0.0f;

    #pragma unroll
    for (int mi = 0; mi < 2; ++mi) {
        #pragma unroll
        for (int ni = 0; ni < 2; ++ni) {
            #pragma unroll
            for (int r = 0; r < 16; ++r) {
                const int rsub = lhalf * 4 + (r & 3) + 8 * (r >> 2);
                float ee = __builtin_amdgcn_exp2f(acc[mi][ni][r] * LSE_SCALE);
                if (mi == ni && dwave && rsub == lrow) ee = 0.0f; // -inf self
                cs[ni] += ee;
                rw[mi][r] += ee;
            }
        }
    }

    // col sums -> colred (4 partials/column, stride-5).
    const int slot = wr * 2 + lhalf;
    #pragma unroll
    for (int ni = 0; ni < 2; ++ni)
        colred[(wc * 64 + ni * 32 + lrow) * 5 + slot] = cs[ni];

    // row partials -> rowbuf[128][68]: all 4 waves, disjoint slots, once.
    if (!diag) {
        #pragma unroll
        for (int mi = 0; mi < 2; ++mi)
            #pragma unroll
            for (int r = 0; r < 16; ++r) {
                const int lr = wr * 64 + mi * 32 + lhalf * 4 + (r & 3) + 8 * (r >> 2);
                rowbuf[lr * 68 + wc * 32 + lrow] = rw[mi][r];
            }
    }
    __syncthreads();   // the ONLY barrier

    if (t < 128) {
        const float s = colred[t * 5 + 0] + colred[t * 5 + 1] +
                        colred[t * 5 + 2] + colred[t * 5 + 3];
        partial[(size_t)rt * TWO_B + (size_t)ct * 128 + t] = s;
    }

    if (!diag) {       // all 256 threads: row = t>>1 covers 0..127
        const int r = t >> 1, h = t & 1;
        const float4* rb = (const float4*)(rowbuf + r * 68 + h * 32);
        float s = 0.0f;
        #pragma unroll
        for (int j = 0; j < 8; ++j) {
            const float4 v = rb[j];
            s += (v.x + v.y) + (v.z + v.w);
        }
        s += __shfl_xor(s, 1, 64);     // combine halves (t, t^1 same wave)
        if (h == 0)
            partial[(size_t)ct * TWO_B + (size_t)rt * 128 + r] = s;
    }
}

// ---------------------------------------------------------------------------
// Kernel 3: per-row sumexp over 64 tile contributions -> lse - pos term.
// 128 blocks: block handles 64 rows; wave w sums 16 tiles for all 64 rows
// (coalesced 256 B loads, 16 independent in flight), one LDS combine, one
// atomic per block.
// ---------------------------------------------------------------------------
__global__ __launch_bounds__(256) void lse_kernel(
    const float* __restrict__ partial, const float* __restrict__ pos,
    float* __restrict__ out)
{
    const int t = threadIdx.x;
    const int wave = t >> 6, lane = t & 63;
    const int row0 = blockIdx.x * 64;

    float s = 0.0f;
    #pragma unroll
    for (int j = 0; j < 16; ++j)
        s += partial[(size_t)(wave * 16 + j) * TWO_B + row0 + lane];

    __shared__ float red[4][64];
    red[wave][lane] = s;
    __syncthreads();

    if (wave == 0) {
        const int row = row0 + lane;
        const float tot = red[0][lane] + red[1][lane] +
                          red[2][lane] + red[3][lane];
        float term = logf(tot) - pos[row & (BATCH - 1)];  // sim_ij == sim_ji
        #pragma unroll
        for (int off = 32; off > 0; off >>= 1)
            term += __shfl_down(term, off);
        if (lane == 0)
            atomicAdd(out, term * (1.0f / (float)TWO_B));
    }
}

// ---------------------------------------------------------------------------
extern "C" void kernel_launch(void* const* d_in, const int* in_sizes, int n_in,
                              void* d_out, int out_size, void* d_ws, size_t ws_size,
                              hipStream_t stream)
{
    const float* p1 = (const float*)d_in[0];
    const float* p2 = (const float*)d_in[1];
    float* out = (float*)d_out;

    // Workspace layout (all fully rewritten every call; poison-safe):
    //   z4t      : 8192*256 fp4 (fragment-ordered) = 2,097,152 B
    //   pos      : 4096 f32                        =    16,384 B
    //   partial  : 64*8192 f32                     = 2,097,152 B
    char* ws = (char*)d_ws;
    unsigned char* z4  = (unsigned char*)ws;
    float* pos         = (float*)(ws + 2097152);
    float* partial     = (float*)(ws + 2097152 + 16384);

    norm_kernel<<<1024, 256, 0, stream>>>(p1, p2, z4, pos, out);
    sim_kernel<<<NTRI, 256, 0, stream>>>(z4, partial);
    lse_kernel<<<128, 256, 0, stream>>>(partial, pos, out);
}

// Round 5
// 85.984 us; speedup vs baseline: 1.0812x; 1.0386x over previous
//
#include <hip/hip_runtime.h>
#include <hip/hip_bf16.h>
#include <math.h>

// Problem constants
#define BATCH   4096
#define DIM     512
#define DIMB    256                         // bytes per fp4 row
#define TWO_B   8192
#define INV_T   10.0f                       // 1/TEMP
#define LSE_SCALE 14.426950408889634f       // log2(e)/TEMP
#define NTRI    2080                        // 64*65/2 upper-triangle tiles

typedef __attribute__((ext_vector_type(8)))  int   intx8;
typedef __attribute__((ext_vector_type(4)))  int   intx4;
typedef __attribute__((ext_vector_type(16))) float floatx16; // 32x32 MFMA acc

// E8M0 scale byte: 2^(x-127). 122 -> 2^-5 per operand (z stored x32; 2^-10
// total undoes 32*32).
#define SCALE_E8M0 122
#define FMT_FP4 4                           // cbsz/blgp encoding for fp4 e2m1

// SESSION LESSONS (measured):
//  - __threadfence() per block => per-XCD L2 writeback: ~+97 us. Never.
//  - 266k device-scope atomics + completion counter: +14 us vs 3-kernel split.
//  - LDS staging in sim loses BOTH ways (per-slab w/ barriers; whole-panel
//    gload_lds + barrier-free ds_read, R3: +6.6 us). Direct-L2 is right.
//  - Flat-unroll all 32 K-loads (R4): +2.9 us vs R2 — 128 prefetch VGPRs
//    cut occupancy 3->2 blocks/CU; latency was NOT the binding constraint.
//  - ACCOUNTING (R0-R4): dur_us tracks TWO 256 MiB harness poison fills
//    (~43 us each, HBM-write-bound, harness-side, un-removable):
//    residuals vs 2x(mean fill): R0 +5.8, R2 +0.4, R3 +6.0, R4 +1.3.
//    => our 3 kernels are largely hidden/overlapped; sim is ~5-10 us, and
//    sim-schedule micro-opts cannot move dur_us. Best config = R2.
//  - THIS ROUND: exact R2 K-loop (2-deep prefetch, (256,3), no setprio) +
//    single-barrier epilogue (1 syncthreads, rowbuf[128][68]=37.4KB, still
//    3 blocks/CU). Pre-commit: ~86 +-1.5 with residual ~0 => ROOFLINE.

// e2m1 encode of |v|<=~6 with round-to-nearest. Values: 0,.5,1,1.5,2,3,4,6.
static __device__ inline unsigned fp4_enc(float v) {
    const unsigned s = (__float_as_uint(v) >> 28) & 8u;   // sign -> bit3
    const float a = fabsf(v);
    unsigned c;
    if      (a < 0.25f) c = 0;
    else if (a < 0.75f) c = 1;
    else if (a < 1.25f) c = 2;
    else if (a < 1.75f) c = 3;
    else if (a < 2.5f)  c = 4;
    else if (a < 3.5f)  c = 5;
    else if (a < 5.0f)  c = 6;
    else                c = 7;
    return s | c;
}

// Fragment-order z4 layout: for global row R and row-byte t (elements
// 2t,2t+1) the byte lives at
//   (R>>5)*8192 + (t>>5)*1024 + ((t>>4)&1)*512 + (R&31)*16 + (t&15)
// so an MFMA A/B fragment load (row-block rb, slab s, lane = r + 32*c) is
// ONE contiguous 1 KB segment: rb*8192 + s*1024 + c*512 + r*16.
static __device__ inline size_t z4t_addr(int R, int t) {
    return (size_t)(R >> 5) * 8192 + (size_t)(t >> 5) * 1024 +
           (size_t)((t >> 4) & 1) * 512 + (size_t)(R & 31) * 16 + (t & 15);
}

// ---------------------------------------------------------------------------
// Kernel 1: L2-normalize pairs. ONE WAVE PER ROW-PAIR (barrier-free):
// lane owns elements 8l..8l+7 (= row-bytes 4l..4l+3, one aligned u32 in
// fragment order). shfl_xor butterfly gives every lane the norms; no LDS,
// no __syncthreads. Also zeroes out[0] (stream-ordered before lse).
// ---------------------------------------------------------------------------
__global__ __launch_bounds__(256) void norm_kernel(
    const float* __restrict__ p1, const float* __restrict__ p2,
    unsigned char* __restrict__ z4, float* __restrict__ pos,
    float* __restrict__ out)
{
    const int wave = threadIdx.x >> 6, lane = threadIdx.x & 63;
    const int i = blockIdx.x * 4 + wave;          // 0..4095

    if (blockIdx.x == 0 && threadIdx.x == 0) out[0] = 0.0f;

    const float4* px = (const float4*)(p1 + (size_t)i * DIM);
    const float4* py = (const float4*)(p2 + (size_t)i * DIM);
    const float4 x0 = px[lane * 2], x1 = px[lane * 2 + 1];
    const float4 y0 = py[lane * 2], y1 = py[lane * 2 + 1];

    float sx = x0.x * x0.x, sy = y0.x * y0.x, sd = x0.x * y0.x;
    sx = fmaf(x0.y, x0.y, sx); sy = fmaf(y0.y, y0.y, sy); sd = fmaf(x0.y, y0.y, sd);
    sx = fmaf(x0.z, x0.z, sx); sy = fmaf(y0.z, y0.z, sy); sd = fmaf(x0.z, y0.z, sd);
    sx = fmaf(x0.w, x0.w, sx); sy = fmaf(y0.w, y0.w, sy); sd = fmaf(x0.w, y0.w, sd);
    sx = fmaf(x1.x, x1.x, sx); sy = fmaf(y1.x, y1.x, sy); sd = fmaf(x1.x, y1.x, sd);
    sx = fmaf(x1.y, x1.y, sx); sy = fmaf(y1.y, y1.y, sy); sd = fmaf(x1.y, y1.y, sd);
    sx = fmaf(x1.z, x1.z, sx); sy = fmaf(y1.z, y1.z, sy); sd = fmaf(x1.z, y1.z, sd);
    sx = fmaf(x1.w, x1.w, sx); sy = fmaf(y1.w, y1.w, sy); sd = fmaf(x1.w, y1.w, sd);

    #pragma unroll
    for (int off = 1; off < 64; off <<= 1) {      // butterfly: all lanes get sums
        sx += __shfl_xor(sx, off);
        sy += __shfl_xor(sy, off);
        sd += __shfl_xor(sd, off);
    }

    const float rx = 1.0f / fmaxf(sqrtf(sx), 1e-12f);
    const float ry = 1.0f / fmaxf(sqrtf(sy), 1e-12f);
    const float gx = 32.0f * rx, gy = 32.0f * ry; // x32 -> sigma ~1.4 in fp4

    const float xs[8] = {x0.x, x0.y, x0.z, x0.w, x1.x, x1.y, x1.z, x1.w};
    const float ys[8] = {y0.x, y0.y, y0.z, y0.w, y1.x, y1.y, y1.z, y1.w};
    unsigned zx = 0, zy = 0;
    #pragma unroll
    for (int j = 0; j < 8; ++j) {
        zx |= fp4_enc(xs[j] * gx) << (4 * j);
        zy |= fp4_enc(ys[j] * gy) << (4 * j);
    }
    // bytes 4l..4l+3 are contiguous & 4-aligned in fragment order
    *(unsigned*)(z4 + z4t_addr(i, lane * 4)) = zx;
    *(unsigned*)(z4 + z4t_addr(i + BATCH, lane * 4)) = zy;

    if (lane == 0) pos[i] = sd * rx * ry * INV_T;
}

// ---------------------------------------------------------------------------
// Kernel 2: UPPER-TRIANGLE fused z@z^T tiles in MX-FP4, direct-L2 K-loop,
// 2-deep register prefetch (exact R2 structure - the best-measured config;
// no setprio, (256,3)). Fragments gathered straight from fragment-ordered
// z4t: one coalesced 1 KB global_load_dwordx4 per wave per fragment, no LDS,
// no barriers in the K-loop.
// Epilogue: exp2 + diag mask; colsum in-lane; rowsum via SINGLE-PHASE LDS
// transpose (rowbuf[128][68] holds all rows; ONE __syncthreads); plain
// stores (every slot written exactly once -> deterministic, no atomics).
// ---------------------------------------------------------------------------
__global__ __launch_bounds__(256, 3) void sim_kernel(
    const unsigned char* __restrict__ z4, float* __restrict__ partial)
{
    __shared__ __align__(16) unsigned char smem[37376];
    float* rowbuf = (float*)smem;               // [128][68] f32 = 34816 B
    float* colred = (float*)(smem + 34816);     // [128*5]  f32 =  2560 B

    // --- triangular decode: blockIdx.x -> (rt, ct), rt <= ct --------------
    const int idx = blockIdx.x;
    int rt = (int)((129.0 - sqrt(16641.0 - 8.0 * (double)idx)) * 0.5);
    while (64 * (rt + 1) - ((rt + 1) * rt) / 2 <= idx) ++rt;
    while (64 * rt - (rt * (rt - 1)) / 2 > idx) --rt;
    const int ct = rt + (idx - (64 * rt - (rt * (rt - 1)) / 2));
    const bool diag = (rt == ct);

    const int t = threadIdx.x;
    const int wave = t >> 6, lane = t & 63;
    const int wr = wave >> 1, wc = wave & 1;   // 2x2 wave grid, 64x64 each
    const int lrow  = lane & 31;               // m/n within a 32-tile
    const int lhalf = lane >> 5;               // k-half (chunk) selector

    // Per-lane byte offset within a (row-block, slab) 1 KB segment.
    const int loff = lhalf * 512 + lrow * 16;
    const unsigned char* Abase = z4 + (size_t)(rt * 4 + wr * 2) * 8192 + loff;
    const unsigned char* Bbase = z4 + (size_t)(ct * 4 + wc * 2) * 8192 + loff;

    floatx16 acc[2][2];
    #pragma unroll
    for (int mi = 0; mi < 2; ++mi)
        #pragma unroll
        for (int ni = 0; ni < 2; ++ni)
            acc[mi][ni] = (floatx16)0.0f;

    // --- barrier-free K-loop: 8 slabs, 2-deep register prefetch -----------
    intx8 af[2], bf[2];
    #pragma unroll
    for (int mi = 0; mi < 2; ++mi) { af[mi] = (intx8)0; bf[mi] = (intx8)0; }

    intx4 pa[2][2], pb[2][2];                   // [buf][mi]
    #pragma unroll
    for (int mi = 0; mi < 2; ++mi) {
        pa[0][mi] = *(const intx4*)(Abase + mi * 8192);
        pb[0][mi] = *(const intx4*)(Bbase + mi * 8192);
    }

    #pragma unroll
    for (int s = 0; s < 8; ++s) {
        const int cur = s & 1, nxt = cur ^ 1;   // compile-time after unroll
        if (s < 7) {
            #pragma unroll
            for (int mi = 0; mi < 2; ++mi) {
                pa[nxt][mi] = *(const intx4*)(Abase + mi * 8192 + (s + 1) * 1024);
                pb[nxt][mi] = *(const intx4*)(Bbase + mi * 8192 + (s + 1) * 1024);
            }
        }
        #pragma unroll
        for (int mi = 0; mi < 2; ++mi)
            #pragma unroll
            for (int j = 0; j < 4; ++j) {       // upper 4 ints stay zero
                af[mi][j] = pa[cur][mi][j];
                bf[mi][j] = pb[cur][mi][j];
            }
        #pragma unroll
        for (int mi = 0; mi < 2; ++mi)
            #pragma unroll
            for (int ni = 0; ni < 2; ++ni)
                acc[mi][ni] = __builtin_amdgcn_mfma_scale_f32_32x32x64_f8f6f4(
                    af[mi], bf[ni], acc[mi][ni],
                    FMT_FP4, FMT_FP4,           // cbsz, blgp = fp4 e2m1
                    0, SCALE_E8M0,              // opsel_a, scale_a (2^-5)
                    0, SCALE_E8M0);             // opsel_b, scale_b (2^-5)
    }

    // --- epilogue ----------------------------------------------------------
    // C/D layout (shape-determined): col = lane&31,
    // row = (reg&3) + 8*(reg>>2) + 4*(lane>>5), within each 32x32 tile.
    // Self-mask only possible when wr==wc && mi==ni && rsub==lrow.
    const bool dwave = diag && (wr == wc);

    float cs[2] = {0.0f, 0.0f};     // per-column sums (2 cols this lane owns)
    float rw[2][16];                // per-row partials (summed over ni in-lane)
    #pragma unroll
    for (int mi = 0; mi < 2; ++mi)
        #pragma unroll
        for (int r = 0; r < 16; ++r)
            rw[mi][r] = 0.0f;

    #pragma unroll
    for (int mi = 0; mi < 2; ++mi) {
        #pragma unroll
        for (int ni = 0; ni < 2; ++ni) {
            #pragma unroll
            for (int r = 0; r < 16; ++r) {
                const int rsub = lhalf * 4 + (r & 3) + 8 * (r >> 2);
                float ee = __builtin_amdgcn_exp2f(acc[mi][ni][r] * LSE_SCALE);
                if (mi == ni && dwave && rsub == lrow) ee = 0.0f; // -inf self
                cs[ni] += ee;
                rw[mi][r] += ee;
            }
        }
    }

    // col sums -> colred (4 partials/column, stride-5).
    const int slot = wr * 2 + lhalf;
    #pragma unroll
    for (int ni = 0; ni < 2; ++ni)
        colred[(wc * 64 + ni * 32 + lrow) * 5 + slot] = cs[ni];

    // row partials -> rowbuf[128][68]: all 4 waves, disjoint slots, once.
    if (!diag) {
        #pragma unroll
        for (int mi = 0; mi < 2; ++mi)
            #pragma unroll
            for (int r = 0; r < 16; ++r) {
                const int lr = wr * 64 + mi * 32 + lhalf * 4 + (r & 3) + 8 * (r >> 2);
                rowbuf[lr * 68 + wc * 32 + lrow] = rw[mi][r];
            }
    }
    __syncthreads();   // the ONLY barrier

    if (t < 128) {
        const float s = colred[t * 5 + 0] + colred[t * 5 + 1] +
                        colred[t * 5 + 2] + colred[t * 5 + 3];
        partial[(size_t)rt * TWO_B + (size_t)ct * 128 + t] = s;
    }

    if (!diag) {       // all 256 threads: row = t>>1 covers 0..127
        const int r = t >> 1, h = t & 1;
        const float4* rb = (const float4*)(rowbuf + r * 68 + h * 32);
        float s = 0.0f;
        #pragma unroll
        for (int j = 0; j < 8; ++j) {
            const float4 v = rb[j];
            s += (v.x + v.y) + (v.z + v.w);
        }
        s += __shfl_xor(s, 1, 64);     // combine halves (t, t^1 same wave)
        if (h == 0)
            partial[(size_t)ct * TWO_B + (size_t)rt * 128 + r] = s;
    }
}

// ---------------------------------------------------------------------------
// Kernel 3: per-row sumexp over 64 tile contributions -> lse - pos term.
// 128 blocks: block handles 64 rows; wave w sums 16 tiles for all 64 rows
// (coalesced 256 B loads, 16 independent in flight), one LDS combine, one
// atomic per block.
// ---------------------------------------------------------------------------
__global__ __launch_bounds__(256) void lse_kernel(
    const float* __restrict__ partial, const float* __restrict__ pos,
    float* __restrict__ out)
{
    const int t = threadIdx.x;
    const int wave = t >> 6, lane = t & 63;
    const int row0 = blockIdx.x * 64;

    float s = 0.0f;
    #pragma unroll
    for (int j = 0; j < 16; ++j)
        s += partial[(size_t)(wave * 16 + j) * TWO_B + row0 + lane];

    __shared__ float red[4][64];
    red[wave][lane] = s;
    __syncthreads();

    if (wave == 0) {
        const int row = row0 + lane;
        const float tot = red[0][lane] + red[1][lane] +
                          red[2][lane] + red[3][lane];
        float term = logf(tot) - pos[row & (BATCH - 1)];  // sim_ij == sim_ji
        #pragma unroll
        for (int off = 32; off > 0; off >>= 1)
            term += __shfl_down(term, off);
        if (lane == 0)
            atomicAdd(out, term * (1.0f / (float)TWO_B));
    }
}

// ---------------------------------------------------------------------------
extern "C" void kernel_launch(void* const* d_in, const int* in_sizes, int n_in,
                              void* d_out, int out_size, void* d_ws, size_t ws_size,
                              hipStream_t stream)
{
    const float* p1 = (const float*)d_in[0];
    const float* p2 = (const float*)d_in[1];
    float* out = (float*)d_out;

    // Workspace layout (all fully rewritten every call; poison-safe):
    //   z4t      : 8192*256 fp4 (fragment-ordered) = 2,097,152 B
    //   pos      : 4096 f32                        =    16,384 B
    //   partial  : 64*8192 f32                     = 2,097,152 B
    char* ws = (char*)d_ws;
    unsigned char* z4  = (unsigned char*)ws;
    float* pos         = (float*)(ws + 2097152);
    float* partial     = (float*)(ws + 2097152 + 16384);

    norm_kernel<<<1024, 256, 0, stream>>>(p1, p2, z4, pos, out);
    sim_kernel<<<NTRI, 256, 0, stream>>>(z4, partial);
    lse_kernel<<<128, 256, 0, stream>>>(partial, pos, out);
}